// Round 2
// baseline (1432.360 us; speedup 1.0000x reference)
//
#include <hip/hip_runtime.h>
#include <math.h>

// Problem constants (match reference)
#define BHN   24          // B*H
#define NSEQ  2048
#define DDIM  64
#define NTILE 32          // NSEQ/64
#define ROWS  (BHN*NSEQ)  // 49152

// ws layout (floats)
#define WS_RQ   0
#define WS_RK   49152
#define WS_NC   98304
#define WS_NR   147456
#define WS_NCI  196608
#define WS_NRI  245760
#define WS_RS   294912

__device__ __forceinline__ float wave_reduce_sum(float v) {
  #pragma unroll
  for (int off = 32; off >= 1; off >>= 1) v += __shfl_xor(v, off, 64);
  return v;
}

// ---- Kernel 1: per-row inverse L2 norms for q and k ----
__global__ __launch_bounds__(256) void knorms(const float* __restrict__ q,
                                              const float* __restrict__ k,
                                              float* __restrict__ rq,
                                              float* __restrict__ rk) {
  int row = blockIdx.x * 4 + (threadIdx.x >> 6);  // 4 waves/block, 1 row/wave
  int lane = threadIdx.x & 63;
  bool isK = row >= ROWS;
  int r = isK ? row - ROWS : row;
  const float* src = isK ? k : q;
  float x = src[(size_t)r * DDIM + lane];
  float ss = wave_reduce_sum(x * x);
  if (lane == 0) {
    float inv = 1.0f / fmaxf(sqrtf(ss), 1e-12f);
    (isK ? rk : rq)[r] = inv;
  }
}

// ---- Kernel 2: scores (64x64 tiles) + n_r/n_c partial sums ----
__global__ __launch_bounds__(256) void kscore(const float* __restrict__ q,
                                              const float* __restrict__ k,
                                              const float* __restrict__ rq,
                                              const float* __restrict__ rk,
                                              float* __restrict__ score,
                                              float* __restrict__ nr,
                                              float* __restrict__ nc) {
  int ct = blockIdx.x, rt = blockIdx.y, bh = blockIdx.z;
  float* sbase = score + (size_t)bh * NSEQ * NSEQ;
  int tid = threadIdx.x;

  if (ct > rt) {  // fully masked tile: write zeros, no sums
    float4 z = make_float4(0.f, 0.f, 0.f, 0.f);
    #pragma unroll
    for (int p = 0; p < 4; ++p) {
      int idx = tid + p * 256;
      int row = idx >> 4, c4 = idx & 15;
      *(float4*)&sbase[(size_t)(rt * 64 + row) * NSEQ + ct * 64 + c4 * 4] = z;
    }
    return;
  }

  __shared__ float qsT[64][68];  // [kk][row], padded for alignment/banks
  __shared__ float ksT[64][68];
  __shared__ float rowsum[64];
  __shared__ float colsum[64];
  if (tid < 64) { rowsum[tid] = 0.f; colsum[tid] = 0.f; }

  const float* qb = q + (size_t)bh * NSEQ * DDIM;
  const float* kb = k + (size_t)bh * NSEQ * DDIM;

  #pragma unroll
  for (int p = 0; p < 4; ++p) {
    int idx = tid + p * 256;
    int row = idx >> 4, c4 = idx & 15;
    float4 a = *(const float4*)&qb[(size_t)(rt * 64 + row) * DDIM + c4 * 4];
    float sa = rq[bh * NSEQ + rt * 64 + row];
    qsT[c4 * 4 + 0][row] = a.x * sa;
    qsT[c4 * 4 + 1][row] = a.y * sa;
    qsT[c4 * 4 + 2][row] = a.z * sa;
    qsT[c4 * 4 + 3][row] = a.w * sa;
    float4 b = *(const float4*)&kb[(size_t)(ct * 64 + row) * DDIM + c4 * 4];
    float sb = rk[bh * NSEQ + ct * 64 + row];
    ksT[c4 * 4 + 0][row] = b.x * sb;
    ksT[c4 * 4 + 1][row] = b.y * sb;
    ksT[c4 * 4 + 2][row] = b.z * sb;
    ksT[c4 * 4 + 3][row] = b.w * sb;
  }
  __syncthreads();

  int tx = tid & 15, ty = tid >> 4;
  int r0 = ty * 4, c0 = tx * 4;
  float acc[4][4] = {};
  #pragma unroll 8
  for (int kk = 0; kk < 64; ++kk) {
    float a[4], b[4];
    *(float4*)a = *(const float4*)&qsT[kk][r0];
    *(float4*)b = *(const float4*)&ksT[kk][c0];
    #pragma unroll
    for (int i = 0; i < 4; ++i)
      #pragma unroll
      for (int j = 0; j < 4; ++j) acc[i][j] += a[i] * b[j];
  }

  float rsum[4] = {0.f, 0.f, 0.f, 0.f};
  float csum[4] = {0.f, 0.f, 0.f, 0.f};
  #pragma unroll
  for (int i = 0; i < 4; ++i) {
    int gr = rt * 64 + r0 + i;
    float4 sv;
    float* svp = &sv.x;
    #pragma unroll
    for (int j = 0; j < 4; ++j) {
      int gc = ct * 64 + c0 + j;
      float cosv = fminf(fmaxf(acc[i][j], -1.0f), 1.0f);
      float s = 0.f;
      if (gc <= gr) {                    // unmasked (mask = strictly above diag)
        float g = acosf(cosv);           // SPHERE_RADIUS = 1
        s = powf(1.0f + g, -65.5f);      // (1+g/sqrt(BW))^-(D+alpha)
      }
      svp[j] = s;
      rsum[i] += s;
      csum[j] += s;
    }
    *(float4*)&sbase[(size_t)gr * NSEQ + ct * 64 + c0] = sv;
  }
  #pragma unroll
  for (int i = 0; i < 4; ++i) atomicAdd(&rowsum[r0 + i], rsum[i]);
  #pragma unroll
  for (int j = 0; j < 4; ++j) atomicAdd(&colsum[c0 + j], csum[j]);
  __syncthreads();
  if (tid < 64) {
    atomicAdd(&nr[bh * NSEQ + rt * 64 + tid], rowsum[tid]);
    atomicAdd(&nc[bh * NSEQ + ct * 64 + tid], colsum[tid]);
  }
}

// ---- Kernel 3: n^{-1/2} ----
__global__ void kinv(const float* __restrict__ nr, const float* __restrict__ nc,
                     float* __restrict__ nrinv, float* __restrict__ ncinv, int n) {
  int i = blockIdx.x * 256 + threadIdx.x;
  if (i < n) {
    nrinv[i] = 1.0f / sqrtf(nr[i]);
    ncinv[i] = 1.0f / sqrtf(nc[i]);
  }
}

// ---- Kernel 4: per-row s2 = sum(score*ncinv) -> rs row scale ----
__global__ __launch_bounds__(256) void krow(const float* __restrict__ score,
                                            const float* __restrict__ ncinv,
                                            const float* __restrict__ nrinv,
                                            float* __restrict__ rs) {
  int rr = blockIdx.x;                  // 0..ROWS
  int bh = rr >> 11, n = rr & (NSEQ - 1);
  const float* srow = score + (size_t)bh * NSEQ * NSEQ + (size_t)n * NSEQ;
  const float* civ = ncinv + bh * NSEQ;
  int tid = threadIdx.x;
  float s = 0.f;
  #pragma unroll
  for (int p = 0; p < 2; ++p) {
    int m4 = tid + p * 256;
    float4 sc = *(const float4*)&srow[m4 * 4];
    float4 ci = *(const float4*)&civ[m4 * 4];
    s += sc.x * ci.x + sc.y * ci.y + sc.z * ci.z + sc.w * ci.w;
  }
  s = wave_reduce_sum(s);
  __shared__ float wsum[4];
  if ((tid & 63) == 0) wsum[tid >> 6] = s;
  __syncthreads();
  if (tid == 0) {
    float tot = wsum[0] + wsum[1] + wsum[2] + wsum[3];
    float ni = nrinv[rr];
    float denom = fmaxf(ni * tot, 1e-12f);
    rs[rr] = ni / denom;
  }
}

// ---- Kernel 5: finalize weights in place + output = W @ V ----
__global__ __launch_bounds__(256) void kout(float* __restrict__ score,
                                            const float* __restrict__ v,
                                            const float* __restrict__ ncinv,
                                            const float* __restrict__ rs,
                                            float* __restrict__ out) {
  int rt = blockIdx.x, bh = blockIdx.y;
  float* sbase = score + (size_t)bh * NSEQ * NSEQ;
  const float* vb = v + (size_t)bh * NSEQ * DDIM;
  int tid = threadIdx.x;
  int tx = tid & 15, ty = tid >> 4;
  int r0 = ty * 4, c0 = tx * 4;

  __shared__ float wT[64][68];  // [m][row]
  __shared__ float vs[64][68];  // [m][d]
  float acc[4][4] = {};

  for (int mt = 0; mt <= rt; ++mt) {
    __syncthreads();
    #pragma unroll
    for (int p = 0; p < 4; ++p) {
      int idx = tid + p * 256;
      int row = idx >> 4, c4 = idx & 15;
      int gr = rt * 64 + row;
      size_t off = (size_t)gr * NSEQ + mt * 64 + c4 * 4;
      float4 sc = *(const float4*)&sbase[off];
      float rscale = rs[bh * NSEQ + gr];
      float4 ci = *(const float4*)&ncinv[bh * NSEQ + mt * 64 + c4 * 4];
      float4 w;
      w.x = sc.x * ci.x * rscale;
      w.y = sc.y * ci.y * rscale;
      w.z = sc.z * ci.z * rscale;
      w.w = sc.w * ci.w * rscale;
      *(float4*)&sbase[off] = w;       // final attn_weights in place
      wT[c4 * 4 + 0][row] = w.x;
      wT[c4 * 4 + 1][row] = w.y;
      wT[c4 * 4 + 2][row] = w.z;
      wT[c4 * 4 + 3][row] = w.w;
      float4 vv = *(const float4*)&vb[(size_t)(mt * 64 + row) * DDIM + c4 * 4];
      *(float4*)&vs[row][c4 * 4] = vv;
    }
    __syncthreads();
    #pragma unroll 8
    for (int kk = 0; kk < 64; ++kk) {
      float a[4], b[4];
      *(float4*)a = *(const float4*)&wT[kk][r0];
      *(float4*)b = *(const float4*)&vs[kk][c0];
      #pragma unroll
      for (int i = 0; i < 4; ++i)
        #pragma unroll
        for (int j = 0; j < 4; ++j) acc[i][j] += a[i] * b[j];
    }
  }
  #pragma unroll
  for (int i = 0; i < 4; ++i) {
    int gr = rt * 64 + r0 + i;
    float4 o = make_float4(acc[i][0], acc[i][1], acc[i][2], acc[i][3]);
    *(float4*)&out[(size_t)bh * NSEQ * DDIM + (size_t)gr * DDIM + c0] = o;
  }
}

extern "C" void kernel_launch(void* const* d_in, const int* in_sizes, int n_in,
                              void* d_out, int out_size, void* d_ws, size_t ws_size,
                              hipStream_t stream) {
  const float* q = (const float*)d_in[0];
  const float* k = (const float*)d_in[1];
  const float* v = (const float*)d_in[2];
  // d_in[3] = attn_mask (bool causal) -- known statically, unused

  float* out = (float*)d_out;                       // [B,H,N,D]
  float* attnw = out + (size_t)BHN * NSEQ * DDIM;   // [B,H,N,N] (also score scratch)
  float* ws = (float*)d_ws;

  float* rq = ws + WS_RQ;
  float* rk = ws + WS_RK;
  float* nc = ws + WS_NC;
  float* nr = ws + WS_NR;
  float* nci = ws + WS_NCI;
  float* nri = ws + WS_NRI;
  float* rs = ws + WS_RS;

  // zero n_c / n_r accumulators (ws is poisoned before each call)
  hipMemsetAsync(nc, 0, (size_t)2 * ROWS * sizeof(float), stream);

  knorms<<<2 * ROWS / 4, 256, 0, stream>>>(q, k, rq, rk);
  kscore<<<dim3(NTILE, NTILE, BHN), 256, 0, stream>>>(q, k, rq, rk, attnw, nr, nc);
  kinv<<<(ROWS + 255) / 256, 256, 0, stream>>>(nr, nc, nri, nci, ROWS);
  krow<<<ROWS, 256, 0, stream>>>(attnw, nci, nri, rs);
  kout<<<dim3(NTILE, BHN), 256, 0, stream>>>(attnw, v, nci, rs, out);
}

// Round 4
// 1190.779 us; speedup vs baseline: 1.2029x; 1.2029x over previous
//
#include <hip/hip_runtime.h>
#include <math.h>

// Problem constants (match reference)
#define BHN   24          // B*H
#define NSEQ  2048
#define DDIM  64
#define NTILE 32          // NSEQ/64
#define ROWS  (BHN*NSEQ)  // 49152

// ws layout (floats)
#define WS_RQ   0
#define WS_RK   49152
#define WS_NC   98304
#define WS_NR   147456
#define WS_NCI  196608
#define WS_NRI  245760
#define WS_RS   294912

__device__ __forceinline__ float wave_reduce_sum(float v) {
  #pragma unroll
  for (int off = 32; off >= 1; off >>= 1) v += __shfl_xor(v, off, 64);
  return v;
}

// fast acos: A&S 4.4.46, abs err <= 2e-8 rad. 7 FMA + v_sqrt + select.
__device__ __forceinline__ float acos_fast(float x) {
  float ax = fabsf(x);
  float p = fmaf(ax, -0.0012624911f, 0.0066700901f);
  p = fmaf(p, ax, -0.0170881256f);
  p = fmaf(p, ax, 0.0308918810f);
  p = fmaf(p, ax, -0.0501743046f);
  p = fmaf(p, ax, 0.0889789874f);
  p = fmaf(p, ax, -0.2145988016f);
  p = fmaf(p, ax, 1.5707963050f);
  float t = __builtin_amdgcn_sqrtf(1.0f - ax);
  float r = t * p;
  return (x >= 0.0f) ? r : (3.14159265358979f - r);
}

// score = (1 + acos(clamp(c)))^-65.5, zeroed when masked
// v_exp_f32 computes 2^x, v_log_f32 computes log2(x) — hardware instrs.
__device__ __forceinline__ float score_fast(float c, bool unmasked) {
  float cosv = fminf(fmaxf(c, -1.0f), 1.0f);
  float g = acos_fast(cosv);
  float s = __builtin_amdgcn_exp2f(-65.5f * __builtin_amdgcn_logf(1.0f + g));
  return unmasked ? s : 0.0f;
}

// ---- Kernel 1: per-row inverse L2 norms for q and k ----
__global__ __launch_bounds__(256) void knorms(const float* __restrict__ q,
                                              const float* __restrict__ k,
                                              float* __restrict__ rq,
                                              float* __restrict__ rk) {
  int row = blockIdx.x * 4 + (threadIdx.x >> 6);  // 4 waves/block, 1 row/wave
  int lane = threadIdx.x & 63;
  bool isK = row >= ROWS;
  int r = isK ? row - ROWS : row;
  const float* src = isK ? k : q;
  float x = src[(size_t)r * DDIM + lane];
  float ss = wave_reduce_sum(x * x);
  if (lane == 0) {
    float inv = 1.0f / fmaxf(sqrtf(ss), 1e-12f);
    (isK ? rk : rq)[r] = inv;
  }
}

// ---- Kernel 2: scores (64x64 tiles) + n_r/n_c partial sums ----
__global__ __launch_bounds__(256) void kscore(const float* __restrict__ q,
                                              const float* __restrict__ k,
                                              const float* __restrict__ rq,
                                              const float* __restrict__ rk,
                                              float* __restrict__ score,
                                              float* __restrict__ nr,
                                              float* __restrict__ nc) {
  int ct = blockIdx.x, rt = blockIdx.y, bh = blockIdx.z;
  float* sbase = score + (size_t)bh * NSEQ * NSEQ;
  int tid = threadIdx.x;

  if (ct > rt) {  // fully masked tile: write zeros, no sums
    float4 z = make_float4(0.f, 0.f, 0.f, 0.f);
    #pragma unroll
    for (int p = 0; p < 4; ++p) {
      int idx = tid + p * 256;
      int row = idx >> 4, c4 = idx & 15;
      *(float4*)&sbase[(size_t)(rt * 64 + row) * NSEQ + ct * 64 + c4 * 4] = z;
    }
    return;
  }

  __shared__ float qsT[64][68];  // [kk][row], padded for alignment/banks
  __shared__ float ksT[64][68];
  __shared__ float rowsum[64];
  __shared__ float colsum[64];
  if (tid < 64) { rowsum[tid] = 0.f; colsum[tid] = 0.f; }

  const float* qb = q + (size_t)bh * NSEQ * DDIM;
  const float* kb = k + (size_t)bh * NSEQ * DDIM;

  #pragma unroll
  for (int p = 0; p < 4; ++p) {
    int idx = tid + p * 256;
    int row = idx >> 4, c4 = idx & 15;
    float4 a = *(const float4*)&qb[(size_t)(rt * 64 + row) * DDIM + c4 * 4];
    float sa = rq[bh * NSEQ + rt * 64 + row];
    qsT[c4 * 4 + 0][row] = a.x * sa;
    qsT[c4 * 4 + 1][row] = a.y * sa;
    qsT[c4 * 4 + 2][row] = a.z * sa;
    qsT[c4 * 4 + 3][row] = a.w * sa;
    float4 b = *(const float4*)&kb[(size_t)(ct * 64 + row) * DDIM + c4 * 4];
    float sb = rk[bh * NSEQ + ct * 64 + row];
    ksT[c4 * 4 + 0][row] = b.x * sb;
    ksT[c4 * 4 + 1][row] = b.y * sb;
    ksT[c4 * 4 + 2][row] = b.z * sb;
    ksT[c4 * 4 + 3][row] = b.w * sb;
  }
  __syncthreads();

  int tx = tid & 15, ty = tid >> 4;
  int r0 = ty * 4, c0 = tx * 4;
  float acc[4][4] = {};
  #pragma unroll 8
  for (int kk = 0; kk < 64; ++kk) {
    float a[4], b[4];
    *(float4*)a = *(const float4*)&qsT[kk][r0];
    *(float4*)b = *(const float4*)&ksT[kk][c0];
    #pragma unroll
    for (int i = 0; i < 4; ++i)
      #pragma unroll
      for (int j = 0; j < 4; ++j) acc[i][j] += a[i] * b[j];
  }

  float rsum[4] = {0.f, 0.f, 0.f, 0.f};
  float csum[4] = {0.f, 0.f, 0.f, 0.f};
  #pragma unroll
  for (int i = 0; i < 4; ++i) {
    int gr = rt * 64 + r0 + i;
    float4 sv;
    float* svp = &sv.x;
    #pragma unroll
    for (int j = 0; j < 4; ++j) {
      int gc = ct * 64 + c0 + j;
      float s = score_fast(acc[i][j], gc <= gr);
      svp[j] = s;
      rsum[i] += s;
      csum[j] += s;
    }
    *(float4*)&sbase[(size_t)gr * NSEQ + ct * 64 + c0] = sv;
  }
  #pragma unroll
  for (int i = 0; i < 4; ++i) atomicAdd(&rowsum[r0 + i], rsum[i]);
  #pragma unroll
  for (int j = 0; j < 4; ++j) atomicAdd(&colsum[c0 + j], csum[j]);
  __syncthreads();
  if (tid < 64) {
    atomicAdd(&nr[bh * NSEQ + rt * 64 + tid], rowsum[tid]);
    atomicAdd(&nc[bh * NSEQ + ct * 64 + tid], colsum[tid]);
  }
}

// ---- Kernel 3: n^{-1/2} ----
__global__ void kinv(const float* __restrict__ nr, const float* __restrict__ nc,
                     float* __restrict__ nrinv, float* __restrict__ ncinv, int n) {
  int i = blockIdx.x * 256 + threadIdx.x;
  if (i < n) {
    nrinv[i] = 1.0f / sqrtf(nr[i]);
    ncinv[i] = 1.0f / sqrtf(nc[i]);
  }
}

// ---- Kernel 4: per-row s2 = sum(score*ncinv) -> rs row scale ----
__global__ __launch_bounds__(256) void krow(const float* __restrict__ score,
                                            const float* __restrict__ ncinv,
                                            const float* __restrict__ nrinv,
                                            float* __restrict__ rs) {
  int rr = blockIdx.x;                  // 0..ROWS
  int bh = rr >> 11, n = rr & (NSEQ - 1);
  const float* srow = score + (size_t)bh * NSEQ * NSEQ + (size_t)n * NSEQ;
  const float* civ = ncinv + bh * NSEQ;
  int tid = threadIdx.x;
  float s = 0.f;
  #pragma unroll
  for (int p = 0; p < 2; ++p) {
    int m4 = tid + p * 256;
    float4 sc = *(const float4*)&srow[m4 * 4];
    float4 ci = *(const float4*)&civ[m4 * 4];
    s += sc.x * ci.x + sc.y * ci.y + sc.z * ci.z + sc.w * ci.w;
  }
  s = wave_reduce_sum(s);
  __shared__ float wsum[4];
  if ((tid & 63) == 0) wsum[tid >> 6] = s;
  __syncthreads();
  if (tid == 0) {
    float tot = wsum[0] + wsum[1] + wsum[2] + wsum[3];
    float ni = nrinv[rr];
    float denom = fmaxf(ni * tot, 1e-12f);
    rs[rr] = ni / denom;
  }
}

// ---- Kernel 5: finalize weights in place + output = W @ V ----
__global__ __launch_bounds__(256) void kout(float* __restrict__ score,
                                            const float* __restrict__ v,
                                            const float* __restrict__ ncinv,
                                            const float* __restrict__ rs,
                                            float* __restrict__ out) {
  int rt = blockIdx.x, bh = blockIdx.y;
  float* sbase = score + (size_t)bh * NSEQ * NSEQ;
  const float* vb = v + (size_t)bh * NSEQ * DDIM;
  int tid = threadIdx.x;
  int tx = tid & 15, ty = tid >> 4;
  int r0 = ty * 4, c0 = tx * 4;

  __shared__ float wT[64][68];  // [m][row]
  __shared__ float vs[64][68];  // [m][d]
  float acc[4][4] = {};

  for (int mt = 0; mt <= rt; ++mt) {
    __syncthreads();
    #pragma unroll
    for (int p = 0; p < 4; ++p) {
      int idx = tid + p * 256;
      int row = idx >> 4, c4 = idx & 15;
      int gr = rt * 64 + row;
      size_t off = (size_t)gr * NSEQ + mt * 64 + c4 * 4;
      float4 sc = *(const float4*)&sbase[off];
      float rscale = rs[bh * NSEQ + gr];
      float4 ci = *(const float4*)&ncinv[bh * NSEQ + mt * 64 + c4 * 4];
      float4 w;
      w.x = sc.x * ci.x * rscale;
      w.y = sc.y * ci.y * rscale;
      w.z = sc.z * ci.z * rscale;
      w.w = sc.w * ci.w * rscale;
      *(float4*)&sbase[off] = w;       // final attn_weights in place
      wT[c4 * 4 + 0][row] = w.x;
      wT[c4 * 4 + 1][row] = w.y;
      wT[c4 * 4 + 2][row] = w.z;
      wT[c4 * 4 + 3][row] = w.w;
      float4 vv = *(const float4*)&vb[(size_t)(mt * 64 + row) * DDIM + c4 * 4];
      *(float4*)&vs[row][c4 * 4] = vv;
    }
    __syncthreads();
    #pragma unroll 8
    for (int kk = 0; kk < 64; ++kk) {
      float a[4], b[4];
      *(float4*)a = *(const float4*)&wT[kk][r0];
      *(float4*)b = *(const float4*)&vs[kk][c0];
      #pragma unroll
      for (int i = 0; i < 4; ++i)
        #pragma unroll
        for (int j = 0; j < 4; ++j) acc[i][j] += a[i] * b[j];
    }
  }
  #pragma unroll
  for (int i = 0; i < 4; ++i) {
    int gr = rt * 64 + r0 + i;
    float4 o = make_float4(acc[i][0], acc[i][1], acc[i][2], acc[i][3]);
    *(float4*)&out[(size_t)bh * NSEQ * DDIM + (size_t)gr * DDIM + c0] = o;
  }
}

extern "C" void kernel_launch(void* const* d_in, const int* in_sizes, int n_in,
                              void* d_out, int out_size, void* d_ws, size_t ws_size,
                              hipStream_t stream) {
  const float* q = (const float*)d_in[0];
  const float* k = (const float*)d_in[1];
  const float* v = (const float*)d_in[2];
  // d_in[3] = attn_mask (bool causal) -- known statically, unused

  float* out = (float*)d_out;                       // [B,H,N,D]
  float* attnw = out + (size_t)BHN * NSEQ * DDIM;   // [B,H,N,N] (also score scratch)
  float* ws = (float*)d_ws;

  float* rq = ws + WS_RQ;
  float* rk = ws + WS_RK;
  float* nc = ws + WS_NC;
  float* nr = ws + WS_NR;
  float* nci = ws + WS_NCI;
  float* nri = ws + WS_NRI;
  float* rs = ws + WS_RS;

  // zero n_c / n_r accumulators (ws is poisoned before each call)
  (void)hipMemsetAsync(nc, 0, (size_t)2 * ROWS * sizeof(float), stream);

  knorms<<<2 * ROWS / 4, 256, 0, stream>>>(q, k, rq, rk);
  kscore<<<dim3(NTILE, NTILE, BHN), 256, 0, stream>>>(q, k, rq, rk, attnw, nr, nc);
  kinv<<<(ROWS + 255) / 256, 256, 0, stream>>>(nr, nc, nri, nci, ROWS);
  krow<<<ROWS, 256, 0, stream>>>(attnw, nci, nri, rs);
  kout<<<dim3(NTILE, BHN), 256, 0, stream>>>(attnw, v, nci, rs, out);
}

// Round 5
// 1175.844 us; speedup vs baseline: 1.2182x; 1.0127x over previous
//
#include <hip/hip_runtime.h>
#include <math.h>

// Problem constants (match reference)
#define BHN   24          // B*H
#define NSEQ  2048
#define DDIM  64
#define NTILE 32          // NSEQ/64
#define ROWS  (BHN*NSEQ)  // 49152

// ws layout (floats)
#define WS_RQ   0
#define WS_RK   49152
#define WS_NC   98304
#define WS_NR   147456
#define WS_NCI  196608
#define WS_NRI  245760
#define WS_RS   294912

__device__ __forceinline__ float wave_reduce_sum(float v) {
  #pragma unroll
  for (int off = 32; off >= 1; off >>= 1) v += __shfl_xor(v, off, 64);
  return v;
}

// fast acos: A&S 4.4.46, abs err <= 2e-8 rad. 7 FMA + v_sqrt + select.
__device__ __forceinline__ float acos_fast(float x) {
  float ax = fabsf(x);
  float p = fmaf(ax, -0.0012624911f, 0.0066700901f);
  p = fmaf(p, ax, -0.0170881256f);
  p = fmaf(p, ax, 0.0308918810f);
  p = fmaf(p, ax, -0.0501743046f);
  p = fmaf(p, ax, 0.0889789874f);
  p = fmaf(p, ax, -0.2145988016f);
  p = fmaf(p, ax, 1.5707963050f);
  float t = __builtin_amdgcn_sqrtf(1.0f - ax);
  float r = t * p;
  return (x >= 0.0f) ? r : (3.14159265358979f - r);
}

// score = (1 + acos(clamp(c)))^-65.5, zeroed when masked
// v_exp_f32 computes 2^x, v_log_f32 computes log2(x) — hardware instrs.
__device__ __forceinline__ float score_fast(float c, bool unmasked) {
  float cosv = fminf(fmaxf(c, -1.0f), 1.0f);
  float g = acos_fast(cosv);
  float s = __builtin_amdgcn_exp2f(-65.5f * __builtin_amdgcn_logf(1.0f + g));
  return unmasked ? s : 0.0f;
}

// ---- Kernel 1: per-row inverse L2 norms for q and k ----
__global__ __launch_bounds__(256) void knorms(const float* __restrict__ q,
                                              const float* __restrict__ k,
                                              float* __restrict__ rq,
                                              float* __restrict__ rk) {
  int row = blockIdx.x * 4 + (threadIdx.x >> 6);  // 4 waves/block, 1 row/wave
  int lane = threadIdx.x & 63;
  bool isK = row >= ROWS;
  int r = isK ? row - ROWS : row;
  const float* src = isK ? k : q;
  float x = src[(size_t)r * DDIM + lane];
  float ss = wave_reduce_sum(x * x);
  if (lane == 0) {
    float inv = 1.0f / fmaxf(sqrtf(ss), 1e-12f);
    (isK ? rk : rq)[r] = inv;
  }
}

// ---- Kernel 2: scores (64x64 tiles) + n_r/n_c partial sums ----
__global__ __launch_bounds__(256) void kscore(const float* __restrict__ q,
                                              const float* __restrict__ k,
                                              const float* __restrict__ rq,
                                              const float* __restrict__ rk,
                                              float* __restrict__ score,
                                              float* __restrict__ nr,
                                              float* __restrict__ nc) {
  int ct = blockIdx.x, rt = blockIdx.y, bh = blockIdx.z;
  float* sbase = score + (size_t)bh * NSEQ * NSEQ;
  int tid = threadIdx.x;

  if (ct > rt) {  // fully masked tile: write zeros, no sums
    float4 z = make_float4(0.f, 0.f, 0.f, 0.f);
    #pragma unroll
    for (int p = 0; p < 4; ++p) {
      int idx = tid + p * 256;
      int row = idx >> 4, c4 = idx & 15;
      *(float4*)&sbase[(size_t)(rt * 64 + row) * NSEQ + ct * 64 + c4 * 4] = z;
    }
    return;
  }

  __shared__ float qsT[64][68];  // [kk][row], padded for alignment/banks
  __shared__ float ksT[64][68];
  __shared__ float rowsum[64];
  __shared__ float colsum[64];
  if (tid < 64) { rowsum[tid] = 0.f; colsum[tid] = 0.f; }

  const float* qb = q + (size_t)bh * NSEQ * DDIM;
  const float* kb = k + (size_t)bh * NSEQ * DDIM;

  #pragma unroll
  for (int p = 0; p < 4; ++p) {
    int idx = tid + p * 256;
    int row = idx >> 4, c4 = idx & 15;
    float4 a = *(const float4*)&qb[(size_t)(rt * 64 + row) * DDIM + c4 * 4];
    float sa = rq[bh * NSEQ + rt * 64 + row];
    qsT[c4 * 4 + 0][row] = a.x * sa;
    qsT[c4 * 4 + 1][row] = a.y * sa;
    qsT[c4 * 4 + 2][row] = a.z * sa;
    qsT[c4 * 4 + 3][row] = a.w * sa;
    float4 b = *(const float4*)&kb[(size_t)(ct * 64 + row) * DDIM + c4 * 4];
    float sb = rk[bh * NSEQ + ct * 64 + row];
    ksT[c4 * 4 + 0][row] = b.x * sb;
    ksT[c4 * 4 + 1][row] = b.y * sb;
    ksT[c4 * 4 + 2][row] = b.z * sb;
    ksT[c4 * 4 + 3][row] = b.w * sb;
  }
  __syncthreads();

  int tx = tid & 15, ty = tid >> 4;
  int r0 = ty * 4, c0 = tx * 4;
  float acc[4][4] = {};
  #pragma unroll 8
  for (int kk = 0; kk < 64; ++kk) {
    float a[4], b[4];
    *(float4*)a = *(const float4*)&qsT[kk][r0];
    *(float4*)b = *(const float4*)&ksT[kk][c0];
    #pragma unroll
    for (int i = 0; i < 4; ++i)
      #pragma unroll
      for (int j = 0; j < 4; ++j) acc[i][j] += a[i] * b[j];
  }

  float rsum[4] = {0.f, 0.f, 0.f, 0.f};
  float csum[4] = {0.f, 0.f, 0.f, 0.f};
  #pragma unroll
  for (int i = 0; i < 4; ++i) {
    int gr = rt * 64 + r0 + i;
    float4 sv;
    float* svp = &sv.x;
    #pragma unroll
    for (int j = 0; j < 4; ++j) {
      int gc = ct * 64 + c0 + j;
      float s = score_fast(acc[i][j], gc <= gr);
      svp[j] = s;
      rsum[i] += s;
      csum[j] += s;
    }
    *(float4*)&sbase[(size_t)gr * NSEQ + ct * 64 + c0] = sv;
  }
  #pragma unroll
  for (int i = 0; i < 4; ++i) atomicAdd(&rowsum[r0 + i], rsum[i]);
  #pragma unroll
  for (int j = 0; j < 4; ++j) atomicAdd(&colsum[c0 + j], csum[j]);
  __syncthreads();
  if (tid < 64) {
    atomicAdd(&nr[bh * NSEQ + rt * 64 + tid], rowsum[tid]);
    atomicAdd(&nc[bh * NSEQ + ct * 64 + tid], colsum[tid]);
  }
}

// ---- Kernel 3: n^{-1/2} ----
__global__ void kinv(const float* __restrict__ nr, const float* __restrict__ nc,
                     float* __restrict__ nrinv, float* __restrict__ ncinv, int n) {
  int i = blockIdx.x * 256 + threadIdx.x;
  if (i < n) {
    nrinv[i] = 1.0f / sqrtf(nr[i]);
    ncinv[i] = 1.0f / sqrtf(nc[i]);
  }
}

// ---- Kernel 4: per-row s2 = sum(score*ncinv) -> rs row scale ----
// Reads only the causal chunks (cols > n are exact zeros and contribute 0).
__global__ __launch_bounds__(256) void krow(const float* __restrict__ score,
                                            const float* __restrict__ ncinv,
                                            const float* __restrict__ nrinv,
                                            float* __restrict__ rs) {
  int rr = blockIdx.x;                  // 0..ROWS
  int bh = rr >> 11, n = rr & (NSEQ - 1);
  const float* srow = score + (size_t)bh * NSEQ * NSEQ + (size_t)n * NSEQ;
  const float* civ = ncinv + bh * NSEQ;
  int tid = threadIdx.x;
  int nch = (n + 1024) >> 10;           // ceil((n+1)/1024) chunks of 256 float4
  float s = 0.f;
  for (int p = 0; p < nch; ++p) {
    int m4 = tid + p * 256;
    float4 sc = *(const float4*)&srow[m4 * 4];
    float4 ci = *(const float4*)&civ[m4 * 4];
    s += sc.x * ci.x + sc.y * ci.y + sc.z * ci.z + sc.w * ci.w;
  }
  s = wave_reduce_sum(s);
  __shared__ float wsum[4];
  if ((tid & 63) == 0) wsum[tid >> 6] = s;
  __syncthreads();
  if (tid == 0) {
    float tot = wsum[0] + wsum[1] + wsum[2] + wsum[3];
    float ni = nrinv[rr];
    float denom = fmaxf(ni * tot, 1e-12f);
    rs[rr] = ni / denom;
  }
}

// ---- Kernel 5: finalize weights in place + partial W@V, atomic into out ----
// Grid (rt, chunk, bh): chunk handles mt in [chunk*8, chunk*8+8) ∩ [0, rt].
#define MTCH 8
__global__ __launch_bounds__(256) void kout2(float* __restrict__ score,
                                             const float* __restrict__ v,
                                             const float* __restrict__ ncinv,
                                             const float* __restrict__ rs,
                                             float* __restrict__ out) {
  int rt = blockIdx.x, ch = blockIdx.y, bh = blockIdx.z;
  int mt0 = ch * MTCH;
  if (mt0 > rt) return;
  int mt1 = min(rt, mt0 + MTCH - 1);

  float* sbase = score + (size_t)bh * NSEQ * NSEQ;
  const float* vb = v + (size_t)bh * NSEQ * DDIM;
  int tid = threadIdx.x;
  int tx = tid & 15, ty = tid >> 4;
  int r0 = ty * 4, c0 = tx * 4;

  __shared__ float wT[64][68];  // [m][row]
  __shared__ float vs[64][68];  // [m][d]
  float acc[4][4] = {};

  for (int mt = mt0; mt <= mt1; ++mt) {
    __syncthreads();
    #pragma unroll
    for (int p = 0; p < 4; ++p) {
      int idx = tid + p * 256;
      int row = idx >> 4, c4 = idx & 15;
      int gr = rt * 64 + row;
      size_t off = (size_t)gr * NSEQ + mt * 64 + c4 * 4;
      float4 sc = *(const float4*)&sbase[off];
      float rscale = rs[bh * NSEQ + gr];
      float4 ci = *(const float4*)&ncinv[bh * NSEQ + mt * 64 + c4 * 4];
      float4 w;
      w.x = sc.x * ci.x * rscale;
      w.y = sc.y * ci.y * rscale;
      w.z = sc.z * ci.z * rscale;
      w.w = sc.w * ci.w * rscale;
      *(float4*)&sbase[off] = w;       // final attn_weights in place
      wT[c4 * 4 + 0][row] = w.x;
      wT[c4 * 4 + 1][row] = w.y;
      wT[c4 * 4 + 2][row] = w.z;
      wT[c4 * 4 + 3][row] = w.w;
      float4 vv = *(const float4*)&vb[(size_t)(mt * 64 + row) * DDIM + c4 * 4];
      *(float4*)&vs[row][c4 * 4] = vv;
    }
    __syncthreads();
    #pragma unroll 8
    for (int kk = 0; kk < 64; ++kk) {
      float a[4], b[4];
      *(float4*)a = *(const float4*)&wT[kk][r0];
      *(float4*)b = *(const float4*)&vs[kk][c0];
      #pragma unroll
      for (int i = 0; i < 4; ++i)
        #pragma unroll
        for (int j = 0; j < 4; ++j) acc[i][j] += a[i] * b[j];
    }
  }
  #pragma unroll
  for (int i = 0; i < 4; ++i) {
    int gr = rt * 64 + r0 + i;
    float* obase = &out[(size_t)bh * NSEQ * DDIM + (size_t)gr * DDIM + c0];
    #pragma unroll
    for (int j = 0; j < 4; ++j) atomicAdd(&obase[j], acc[i][j]);
  }
}

extern "C" void kernel_launch(void* const* d_in, const int* in_sizes, int n_in,
                              void* d_out, int out_size, void* d_ws, size_t ws_size,
                              hipStream_t stream) {
  const float* q = (const float*)d_in[0];
  const float* k = (const float*)d_in[1];
  const float* v = (const float*)d_in[2];
  // d_in[3] = attn_mask (bool causal) -- known statically, unused

  float* out = (float*)d_out;                       // [B,H,N,D]
  float* attnw = out + (size_t)BHN * NSEQ * DDIM;   // [B,H,N,N] (also score scratch)
  float* ws = (float*)d_ws;

  float* rq = ws + WS_RQ;
  float* rk = ws + WS_RK;
  float* nc = ws + WS_NC;
  float* nr = ws + WS_NR;
  float* nci = ws + WS_NCI;
  float* nri = ws + WS_NRI;
  float* rs = ws + WS_RS;

  // zero n_c/n_r accumulators and the output (kout2 atomically accumulates)
  (void)hipMemsetAsync(nc, 0, (size_t)2 * ROWS * sizeof(float), stream);
  (void)hipMemsetAsync(out, 0, (size_t)BHN * NSEQ * DDIM * sizeof(float), stream);

  knorms<<<2 * ROWS / 4, 256, 0, stream>>>(q, k, rq, rk);
  kscore<<<dim3(NTILE, NTILE, BHN), 256, 0, stream>>>(q, k, rq, rk, attnw, nr, nc);
  kinv<<<(ROWS + 255) / 256, 256, 0, stream>>>(nr, nc, nri, nci, ROWS);
  krow<<<ROWS, 256, 0, stream>>>(attnw, nci, nri, rs);
  kout2<<<dim3(NTILE, NTILE / MTCH, BHN), 256, 0, stream>>>(attnw, v, nci, rs, out);
}